// Round 5
// baseline (31.464 us; speedup 1.0000x reference)
//
#include <hip/hip_runtime.h>

// HybridQAE: analytic encoder (Heisenberg-reduced: RZ drops, CNOT+RY(Z) ->
// products of per-qubit cos/sin) + MFMA MLP 4->16->32->16 (16x16x32_f16,
// fp32 accum). Wave = 2 tiles x 64 samples; both tiles' x loaded up front
// for MLP (memory-level parallelism); LDS scratch reused across tiles
// (per-wave LDS ordering makes sequential reuse safe).

typedef _Float16 f16x8 __attribute__((ext_vector_type(8)));
typedef _Float16 f16x4 __attribute__((ext_vector_type(4)));
typedef float    f32x4 __attribute__((ext_vector_type(4)));

__global__ __launch_bounds__(256) void hqae_kernel(
    const float* __restrict__ x,
    const float* __restrict__ qw,
    const float* __restrict__ W1, const float* __restrict__ b1,
    const float* __restrict__ W2, const float* __restrict__ b2,
    const float* __restrict__ W3, const float* __restrict__ b3,
    float* __restrict__ out)
{
    __shared__ alignas(16) f16x8 sW1h[16];       // [m][k0..7], k>=4 zero
    __shared__ alignas(16) f16x8 sW2h[64];       // (32,16): [row*2 + kblk]
    __shared__ alignas(16) f16x8 sW3h[64];       // (16,32): [row*4 + kblk]
    __shared__ alignas(16) float sb1[16];
    __shared__ alignas(16) float sb2[32];
    __shared__ alignas(16) float sb3[16];
    __shared__ float scw[4], ssw[4];
    __shared__ alignas(16) f16x4 zbuf[4][2][64]; // [wv][tile][sample]
    __shared__ alignas(16) f16x4 sH1[4][256];    // [wv][sample*4 + g]   (reused per tile)
    __shared__ alignas(16) f16x4 sH2[4][512];    // [wv][sample*8 + mt*4 + g]

    const int tid = threadIdx.x;

    _Float16* w1p = (_Float16*)sW1h;
    _Float16* w2p = (_Float16*)sW2h;
    _Float16* w3p = (_Float16*)sW3h;
    for (int t = tid; t < 512; t += 256) {
        w2p[t] = (_Float16)W2[t];
        w3p[t] = (_Float16)W3[t];
    }
    if (tid < 128) w1p[tid] = ((tid & 7) < 4) ? (_Float16)W1[(tid >> 3) * 4 + (tid & 7)]
                                              : (_Float16)0.f;
    if (tid < 16) { sb1[tid] = b1[tid]; sb3[tid] = b3[tid]; }
    if (tid < 32) sb2[tid] = b2[tid];
    if (tid < 4)  { float a = qw[2 * tid]; scw[tid] = __cosf(a); ssw[tid] = __sinf(a); }
    __syncthreads();

    const int wv   = tid >> 6;
    const int lane = tid & 63;
    const int g    = lane >> 4;
    const int ln15 = lane & 15;
    // block covers 512 samples: tile t of wave wv starts at +t*256 + wv*64
    const int base0 = blockIdx.x * 512 + wv * 64;
    const int base1 = base0 + 256;

    // ---------------- load both tiles' features up front ----------------
    const float4* xin0 = reinterpret_cast<const float4*>(x + (size_t)(base0 + lane) * 16);
    const float4* xin1 = reinterpret_cast<const float4*>(x + (size_t)(base1 + lane) * 16);
    float4 a00 = xin0[0], a01 = xin0[1], a02 = xin0[2], a03 = xin0[3];
    float4 a10 = xin1[0], a11 = xin1[1], a12 = xin1[2], a13 = xin1[3];

    const float PI4 = 0.78539816339744831f;      // angle = mean*pi = sum*pi/4
    const float k0 = scw[0], k1 = scw[1], k2 = scw[2], k3 = scw[3];
    const float l0 = ssw[0], l1 = ssw[1], l2 = ssw[2], l3 = ssw[3];

#pragma unroll
    for (int t = 0; t < 2; ++t) {
        float4 b0 = t ? a10 : a00, b1v = t ? a11 : a01;
        float4 b2v = t ? a12 : a02, b3v = t ? a13 : a03;
        float t0 = (b0.x + b0.y + b0.z + b0.w) * PI4;
        float t1 = (b1v.x + b1v.y + b1v.z + b1v.w) * PI4;
        float t2 = (b2v.x + b2v.y + b2v.z + b2v.w) * PI4;
        float t3 = (b3v.x + b3v.y + b3v.z + b3v.w) * PI4;
        float C0 = __cosf(t0), S0 = __sinf(t0);
        float C1 = __cosf(t1), S1 = __sinf(t1);
        float C2 = __cosf(t2), S2 = __sinf(t2);
        float C3 = __cosf(t3), S3 = __sinf(t3);
        float C01 = C0 * C1, C012 = C01 * C2, C0123 = C012 * C3;
        float z0 = k0 * C0    - l0 * (S0 * S1);
        float z1 = k1 * C01   - l1 * (S1 * S2);
        float z2 = k2 * C012  - l2 * (S2 * S3);
        float z3 = k3 * C0123 - l3 * S3;
        f16x4 zv = { (_Float16)z0, (_Float16)z1, (_Float16)z2, (_Float16)z3 };
        zbuf[wv][t][lane] = zv;
    }

    // ---------------- hoisted weight fragments & biases ----------------
    f16x8 aW1 = sW1h[ln15];
    f32x4 bias1 = ((const f32x4*)sb1)[g];
    const int gh = g & 1;
    f16x8 aW2_0 = sW2h[(0 * 16 + ln15) * 2 + gh];
    f16x8 aW2_1 = sW2h[(1 * 16 + ln15) * 2 + gh];
    f32x4 bias2_0 = ((const f32x4*)sb2)[0 * 4 + g];
    f32x4 bias2_1 = ((const f32x4*)sb2)[1 * 4 + g];
    f16x8 bW3 = sW3h[ln15 * 4 + g];
    float b3s = sb3[ln15];
    f32x4 bias3 = { b3s, b3s, b3s, b3s };

#pragma unroll
    for (int t = 0; t < 2; ++t) {
        const int tb = t ? base1 : base0;

        // ---- layer 1: H1(16f x 64s) = W1 . Z  (K=4, zero-padded) ----
#pragma unroll
        for (int st = 0; st < 4; ++st) {
            f16x4 zv = zbuf[wv][t][st * 16 + ln15];
            f16x8 bf = (f16x8)0;
            if (g == 0) { bf[0] = zv[0]; bf[1] = zv[1]; bf[2] = zv[2]; bf[3] = zv[3]; }
            f32x4 d = __builtin_amdgcn_mfma_f32_16x16x32_f16(aW1, bf, bias1, 0, 0, 0);
            f16x4 hv;
#pragma unroll
            for (int r = 0; r < 4; ++r) hv[r] = (_Float16)fmaxf(d[r], 0.f);
            sH1[wv][(st * 16 + ln15) * 4 + g] = hv;
        }

        // ---- layer 2: H2(32f x 64s) = W2 . H1  (K=16, blocks 0,1) ----
#pragma unroll
        for (int st = 0; st < 4; ++st) {
            f16x8 bh = *((const f16x8*)&sH1[wv][(st * 16 + ln15) * 4] + gh);
            if (g >= 2) bh = (f16x8)0;
            f32x4 d0 = __builtin_amdgcn_mfma_f32_16x16x32_f16(aW2_0, bh, bias2_0, 0, 0, 0);
            f32x4 d1 = __builtin_amdgcn_mfma_f32_16x16x32_f16(aW2_1, bh, bias2_1, 0, 0, 0);
            f16x4 hv0, hv1;
#pragma unroll
            for (int r = 0; r < 4; ++r) {
                hv0[r] = (_Float16)fmaxf(d0[r], 0.f);
                hv1[r] = (_Float16)fmaxf(d1[r], 0.f);
            }
            sH2[wv][(st * 16 + ln15) * 8 + 0 * 4 + g] = hv0;
            sH2[wv][(st * 16 + ln15) * 8 + 1 * 4 + g] = hv1;
        }

        // ---- layer 3 swapped: O^T = H2^T . W3^T -> sample-major stores ----
#pragma unroll
        for (int st = 0; st < 4; ++st) {
            f16x8 ah = *((const f16x8*)&sH2[wv][(st * 16 + ln15) * 8] + g);
            f32x4 d = __builtin_amdgcn_mfma_f32_16x16x32_f16(ah, bW3, bias3, 0, 0, 0);
            const size_t srow = (size_t)(tb + st * 16 + g * 4);
#pragma unroll
            for (int r = 0; r < 4; ++r)
                __builtin_nontemporal_store(d[r], &out[(srow + r) * 16 + ln15]);
        }
    }
}

extern "C" void kernel_launch(void* const* d_in, const int* in_sizes, int n_in,
                              void* d_out, int out_size, void* d_ws, size_t ws_size,
                              hipStream_t stream) {
    const float* x  = (const float*)d_in[0];
    const float* qw = (const float*)d_in[1];
    const float* W1 = (const float*)d_in[2];
    const float* b1 = (const float*)d_in[3];
    const float* W2 = (const float*)d_in[4];
    const float* b2 = (const float*)d_in[5];
    const float* W3 = (const float*)d_in[6];
    const float* b3 = (const float*)d_in[7];
    float* out = (float*)d_out;

    const int B = in_sizes[0] / 16;              // 1048576
    hqae_kernel<<<B / 512, 256, 0, stream>>>(x, qw, W1, b1, W2, b2, W3, b3, out);
}

// Round 7
// 26.790 us; speedup vs baseline: 1.1745x; 1.1745x over previous
//
#include <hip/hip_runtime.h>

// HybridQAE: analytic encoder (Heisenberg-reduced: RZ drops out, CNOT+RY ->
// products of per-qubit cos/sin) + MFMA MLP 4->16->32->16 (16x16x32_f16,
// fp32 accum). One wave = 64 samples (lane = sample). All inter-layer
// fragment transposes via ds_bpermute (__shfl) -- zero LDS scratch, zero
// bank conflicts, no barriers. L3 unswapped so D = [feature][sample] and
// each lane stores one contiguous 16B vector (nontemporal).

typedef _Float16 f16x8 __attribute__((ext_vector_type(8)));
typedef _Float16 f16x4 __attribute__((ext_vector_type(4)));
typedef float    f32x4 __attribute__((ext_vector_type(4)));
typedef int      i32x4 __attribute__((ext_vector_type(4)));

__device__ __forceinline__ int2 pack4(float a, float b, float c, float d) {
    f16x4 v = { (_Float16)a, (_Float16)b, (_Float16)c, (_Float16)d };
    return *reinterpret_cast<int2*>(&v);
}
__device__ __forceinline__ f16x8 frag_from(int a, int b, int c, int d) {
    i32x4 v = { a, b, c, d };
    return *reinterpret_cast<f16x8*>(&v);
}

__global__ __launch_bounds__(256) void hqae_kernel(
    const float* __restrict__ x,
    const float* __restrict__ qw,
    const float* __restrict__ W1, const float* __restrict__ b1,
    const float* __restrict__ W2, const float* __restrict__ b2,
    const float* __restrict__ W3, const float* __restrict__ b3,
    float* __restrict__ out)
{
    // ---- weights (block-shared, f16), one-time staging ----
    __shared__ alignas(16) f16x8 sW1h[16];   // [m][k0..7], k>=4 zero
    __shared__ alignas(16) f16x8 sW2h[64];   // (32,16): [row*2 + kblk]
    __shared__ alignas(16) f16x8 sW3h[64];   // (16,32): [row*4 + kblk]
    __shared__ alignas(16) float sb1[16];
    __shared__ alignas(16) float sb2[32];
    __shared__ alignas(16) float sb3[16];
    __shared__ float scw[4], ssw[4];

    const int tid = threadIdx.x;
    _Float16* w1p = (_Float16*)sW1h;
    _Float16* w2p = (_Float16*)sW2h;
    _Float16* w3p = (_Float16*)sW3h;
    for (int t = tid; t < 512; t += 256) {
        w2p[t] = (_Float16)W2[t];
        w3p[t] = (_Float16)W3[t];
    }
    if (tid < 128) w1p[tid] = ((tid & 7) < 4) ? (_Float16)W1[(tid >> 3) * 4 + (tid & 7)]
                                              : (_Float16)0.f;
    if (tid < 16) { sb1[tid] = b1[tid]; sb3[tid] = b3[tid]; }
    if (tid < 32) sb2[tid] = b2[tid];
    if (tid < 4)  { float a = qw[2 * tid]; scw[tid] = __cosf(a); ssw[tid] = __sinf(a); }
    __syncthreads();

    const int wv   = tid >> 6;
    const int lane = tid & 63;
    const int g    = lane >> 4;
    const int ln15 = lane & 15;
    const int base = blockIdx.x * 256 + wv * 64;

    // ---------------- encoder (analytic), lane = sample ----------------
    int2 dz;
    {
        const float4* xin = reinterpret_cast<const float4*>(x + (size_t)(base + lane) * 16);
        float4 a0 = xin[0], a1 = xin[1], a2 = xin[2], a3 = xin[3];
        const float PI4 = 0.78539816339744831f;   // angle = mean*pi = sum*pi/4
        float t0 = (a0.x + a0.y + a0.z + a0.w) * PI4;
        float t1 = (a1.x + a1.y + a1.z + a1.w) * PI4;
        float t2 = (a2.x + a2.y + a2.z + a2.w) * PI4;
        float t3 = (a3.x + a3.y + a3.z + a3.w) * PI4;
        float C0 = __cosf(t0), S0 = __sinf(t0);
        float C1 = __cosf(t1), S1 = __sinf(t1);
        float C2 = __cosf(t2), S2 = __sinf(t2);
        float C3 = __cosf(t3), S3 = __sinf(t3);
        float C01 = C0 * C1, C012 = C01 * C2, C0123 = C012 * C3;
        float z0 = scw[0] * C0    - ssw[0] * (S0 * S1);
        float z1 = scw[1] * C01   - ssw[1] * (S1 * S2);
        float z2 = scw[2] * C012  - ssw[2] * (S2 * S3);
        float z3 = scw[3] * C0123 - ssw[3] * S3;
        dz = pack4(z0, z1, z2, z3);
    }

    // ---------------- hoisted weight fragments & biases ----------------
    f16x8 aW1   = sW1h[ln15];
    f32x4 bias1 = ((const f32x4*)sb1)[g];
    const int gh = g & 1;
    f16x8 aW2_0 = sW2h[(0 * 16 + ln15) * 2 + gh];     // rows 0..15
    f16x8 aW2_1 = sW2h[(1 * 16 + ln15) * 2 + gh];     // rows 16..31
    f32x4 bias2_0 = ((const f32x4*)sb2)[g];
    f32x4 bias2_1 = ((const f32x4*)sb2)[4 + g];
    f16x8 aW3   = sW3h[ln15 * 4 + g];                 // W3 row ln15, k=g*8..+7
    f32x4 bias3 = ((const f32x4*)sb3)[g];

    // shuffle source lanes (st-invariant): feature-pair sources for the
    // [4-rows-per-group]->[8-k-per-group] fragment regroupings
    const int sA = ((g & 1) << 5) + ln15;   // lanes holding features blk*8+0..3
    const int sB = sA + 16;                 // lanes holding features blk*8+4..7

#pragma unroll
    for (int st = 0; st < 4; ++st) {
        // ---- layer 1: H1 = W1 . Z  (K=4 zero-padded) ----
        int src = st * 16 + ln15;
        int zlo = __shfl(dz.x, src), zhi = __shfl(dz.y, src);
        f16x8 bf1 = (g == 0) ? frag_from(zlo, zhi, 0, 0) : (f16x8)0;
        f32x4 d1 = __builtin_amdgcn_mfma_f32_16x16x32_f16(aW1, bf1, bias1, 0, 0, 0);
        int2 h1 = pack4(fmaxf(d1[0], 0.f), fmaxf(d1[1], 0.f),
                        fmaxf(d1[2], 0.f), fmaxf(d1[3], 0.f));

        // ---- layer 2: H2 = W2 . H1  (K=16: k-blocks 0,1) ----
        int b0 = __shfl(h1.x, sA), b1v = __shfl(h1.y, sA);
        int b2v = __shfl(h1.x, sB), b3v = __shfl(h1.y, sB);
        f16x8 bf2 = (g < 2) ? frag_from(b0, b1v, b2v, b3v) : (f16x8)0;
        f32x4 d2a = __builtin_amdgcn_mfma_f32_16x16x32_f16(aW2_0, bf2, bias2_0, 0, 0, 0);
        f32x4 d2b = __builtin_amdgcn_mfma_f32_16x16x32_f16(aW2_1, bf2, bias2_1, 0, 0, 0);
        int2 h2a = pack4(fmaxf(d2a[0], 0.f), fmaxf(d2a[1], 0.f),
                         fmaxf(d2a[2], 0.f), fmaxf(d2a[3], 0.f));   // features 0..15
        int2 h2b = pack4(fmaxf(d2b[0], 0.f), fmaxf(d2b[1], 0.f),
                         fmaxf(d2b[2], 0.f), fmaxf(d2b[3], 0.f));   // features 16..31

        // ---- layer 3: O = W3 . H2  (K=32 full) ----
        int a0 = __shfl(h2a.x, sA), a1 = __shfl(h2a.y, sA);
        int a2 = __shfl(h2a.x, sB), a3 = __shfl(h2a.y, sB);
        int c0 = __shfl(h2b.x, sA), c1 = __shfl(h2b.y, sA);
        int c2 = __shfl(h2b.x, sB), c3 = __shfl(h2b.y, sB);
        f16x8 bf3 = (g < 2) ? frag_from(a0, a1, a2, a3)
                            : frag_from(c0, c1, c2, c3);
        f32x4 d3 = __builtin_amdgcn_mfma_f32_16x16x32_f16(aW3, bf3, bias3, 0, 0, 0);

        // D[row=out-feature g*4+r][col=sample ln15] -> one 16B store per lane
        f32x4* op = reinterpret_cast<f32x4*>(out + (size_t)(base + st * 16 + ln15) * 16 + g * 4);
        __builtin_nontemporal_store(d3, op);
    }
}

extern "C" void kernel_launch(void* const* d_in, const int* in_sizes, int n_in,
                              void* d_out, int out_size, void* d_ws, size_t ws_size,
                              hipStream_t stream) {
    const float* x  = (const float*)d_in[0];
    const float* qw = (const float*)d_in[1];
    const float* W1 = (const float*)d_in[2];
    const float* b1 = (const float*)d_in[3];
    const float* W2 = (const float*)d_in[4];
    const float* b2 = (const float*)d_in[5];
    const float* W3 = (const float*)d_in[6];
    const float* b3 = (const float*)d_in[7];
    float* out = (float*)d_out;

    const int B = in_sizes[0] / 16;              // 1048576
    hqae_kernel<<<B / 256, 256, 0, stream>>>(x, qw, W1, b1, W2, b2, W3, b3, out);
}